// Round 1
// baseline (254.866 us; speedup 1.0000x reference)
//
#include <hip/hip_runtime.h>
#include <stdint.h>

#define F_IN 65536
#define NN 100
#define CO 60
#define KC 512
#define BK 64
#define NIT (KC/BK)
#define NSPLIT (F_IN/KC)
#define AST 72   // A LDS row stride in bf16 elements (144 B: 16B-aligned, 2-way bank alias = free)

typedef short v8s __attribute__((ext_vector_type(8)));
typedef float v4f __attribute__((ext_vector_type(4)));

__device__ __forceinline__ unsigned short f2bf(float x){
  unsigned int u = __float_as_uint(x);
  u += 0x7fffu + ((u>>16)&1u);      // round-to-nearest-even
  return (unsigned short)(u>>16);
}

// ---------------------------------------------------------------------------
// K2: Y[g] = x @ W_g for g in {a0,a1,a2,c0,c1,c2}.  Split-K with atomicAdd.
// grid = (NSPLIT, 3); block = 256.  blockIdx.y = k-slab (gk), shared x-chunk.
// A (x) staged in LDS as bf16; B (W) loaded straight from global in B-frag
// layout (8 dwords/lane, 64B segments), converted to bf16 in registers.
// ---------------------------------------------------------------------------
__global__ __launch_bounds__(256,2)
void k_gemm(const float* __restrict__ x, const float* __restrict__ aw,
            const float* __restrict__ cw, float* __restrict__ Y){
  const int ksplit = blockIdx.x;
  const int gk = blockIdx.y;
  const int k0 = ksplit*KC;
  const int tid = threadIdx.x;
  const int wave = tid>>6, lane = tid&63, quad = lane>>4, nl = lane&15;
  const int c0 = wave*16;                 // wave w handles cols 16w..16w+15 of both nets
  const int ccl = min(c0+nl, CO-1);       // clamp pad lanes (c>=60) to col 59; discarded later

  __shared__ __align__(16) unsigned short Al[112*AST];

  const float* ap = aw + (size_t)gk*F_IN*CO + (size_t)(k0 + quad*8)*CO + ccl;
  const float* cp = cw + (size_t)gk*F_IN*CO + (size_t)(k0 + quad*8)*CO + ccl;

  v4f accA[7], accC[7];
  #pragma unroll
  for(int i=0;i<7;i++){
    v4f z = {0.f,0.f,0.f,0.f};
    accA[i]=z; accC[i]=z;
  }

  for(int it=0; it<NIT; ++it){
    const int kb = k0 + it*BK;
    // --- B loads first (pure global, no LDS dependency) ---
    float bA[16], bC[16];                 // [ks*8 + j]
    #pragma unroll
    for(int u=0; u<16; ++u){
      const int koff = (it*BK + (u>>3)*32 + (u&7))*CO;
      bA[u] = ap[koff];
      bC[u] = cp[koff];
    }
    // --- stage A tile (112 rows x 64 k) as bf16 into LDS ---
    #pragma unroll
    for(int p=0;p<7;++p){
      int lin = p*256 + tid;              // 0..1791
      int row = lin>>4, q = lin&15;
      int rcl = min(row, NN-1);           // rows 100..111 clone row 99; outputs discarded
      const float4 v = *(const float4*)(x + (size_t)rcl*F_IN + kb + q*4);
      uint2 w;
      w.x = (unsigned)f2bf(v.x) | ((unsigned)f2bf(v.y)<<16);
      w.y = (unsigned)f2bf(v.z) | ((unsigned)f2bf(v.w)<<16);
      ((uint2*)Al)[row*18 + q];           // (address formation aid; real store below)
      ((uint2*)Al)[row*18 + q] = w;
    }
    __syncthreads();
    // --- build B fragments (bf16) ---
    v8s fA0,fA1,fC0,fC1;
    #pragma unroll
    for(int j=0;j<8;++j){
      fA0[j]=(short)f2bf(bA[j]);   fA1[j]=(short)f2bf(bA[8+j]);
      fC0[j]=(short)f2bf(bC[j]);   fC1[j]=(short)f2bf(bC[8+j]);
    }
    // --- MFMA over 7 m-tiles (M padded 100->112) ---
    #pragma unroll
    for(int mt=0; mt<7; ++mt){
      const unsigned short* arow = Al + (mt*16+nl)*AST + quad*8;
      v8s a0 = *(const v8s*)(arow);       // k = quad*8 + j
      v8s a1 = *(const v8s*)(arow+32);    // k = 32 + quad*8 + j
      accA[mt] = __builtin_amdgcn_mfma_f32_16x16x32_bf16(a0,fA0,accA[mt],0,0,0);
      accA[mt] = __builtin_amdgcn_mfma_f32_16x16x32_bf16(a1,fA1,accA[mt],0,0,0);
      accC[mt] = __builtin_amdgcn_mfma_f32_16x16x32_bf16(a0,fC0,accC[mt],0,0,0);
      accC[mt] = __builtin_amdgcn_mfma_f32_16x16x32_bf16(a1,fC1,accC[mt],0,0,0);
    }
    __syncthreads();
  }
  // --- epilogue: split-K accumulate. C/D layout: col=lane&15, row=quad*4+i ---
  const int c = c0 + nl;
  if (c < CO){
    #pragma unroll
    for(int mt=0; mt<7; ++mt){
      #pragma unroll
      for(int i=0;i<4;++i){
        int m = mt*16 + quad*4 + i;
        if (m < NN){
          atomicAdd(&Y[(size_t)gk*NN*CO     + m*CO + c], accA[mt][i]);
          atomicAdd(&Y[(size_t)(3+gk)*NN*CO + m*CO + c], accC[mt][i]);
        }
      }
    }
  }
}

// ---------------------------------------------------------------------------
// K3: cheb combine.  out = Y0 - Y2 + L@(Y1 + 2*L@Y2) + b, then tanh.
// One block per (net, output column c).  L (100x100) rebuilt in LDS per block.
// ---------------------------------------------------------------------------
__global__ void k_cheb(const float* __restrict__ Y, const int* __restrict__ ei,
                       const float* __restrict__ ab, const float* __restrict__ cb,
                       float* __restrict__ emb){
  const int net = blockIdx.x / CO;
  const int c   = blockIdx.x % CO;
  const int t   = threadIdx.x;       // 128
  __shared__ float L[NN][NN+1];      // +1 pad: stride 101 -> 2-way bank alias only
  __shared__ float dis[NN];
  __shared__ int   deg[NN];
  __shared__ float y0[NN], y1[NN], y2[NN], zu[NN];

  for(int i=t;i<NN*(NN+1);i+=128) ((float*)L)[i]=0.f;
  if(t<NN) deg[t]=0;
  __syncthreads();
  for(int e=t;e<2000;e+=128) atomicAdd(&deg[ei[e]],1);   // deg = segment_sum over src
  __syncthreads();
  if(t<NN) dis[t] = deg[t]>0 ? rsqrtf((float)deg[t]) : 0.f;
  __syncthreads();
  for(int e=t;e<2000;e+=128){
    int s = ei[e], d = ei[2000+e];
    atomicAdd(&L[d][s], -dis[s]*dis[d]);                 // duplicates accumulate, as segment_sum
  }
  if(t<NN){
    const float* yb = Y + (size_t)net*3*NN*CO + t*CO + c;
    y0[t]=yb[0]; y1[t]=yb[NN*CO]; y2[t]=yb[2*NN*CO];
  }
  __syncthreads();
  if(t<NN){
    float s=0.f;
    #pragma unroll 4
    for(int j=0;j<NN;++j) s += L[t][j]*y2[j];
    zu[t] = y1[t] + 2.f*s;
  }
  __syncthreads();
  if(t<NN){
    float s=0.f;
    #pragma unroll 4
    for(int j=0;j<NN;++j) s += L[t][j]*zu[j];
    float b = (net==0) ? ab[c] : cb[c];
    emb[net*NN*CO + t*CO + c] = tanhf(y0[t] - y2[t] + s + b);
  }
}

// ---------------------------------------------------------------------------
// K4: final FC.  blocks 0..99: logits[j]; block 100: value.
// ---------------------------------------------------------------------------
__global__ void k_fc(const float* __restrict__ emb, const float* __restrict__ afw,
                     const float* __restrict__ afb, const float* __restrict__ cfw,
                     const float* __restrict__ cfb, const float* __restrict__ s0,
                     const float* __restrict__ s1, const float* __restrict__ s2,
                     float* __restrict__ out){
  const int j = blockIdx.x;          // 0..100
  const int t = threadIdx.x;         // 256
  float p = 0.f;
  if(j < 100){
    for(int i=t;i<6000;i+=256) p += emb[i]*afw[(size_t)i*100 + j];
  } else {
    const float* e = emb + 6000;
    for(int i=t;i<6000;i+=256) p += e[i]*cfw[i];
  }
  #pragma unroll
  for(int o=32;o>0;o>>=1) p += __shfl_down(p,o,64);
  __shared__ float red[4];
  if((t&63)==0) red[t>>6]=p;
  __syncthreads();
  if(t==0){
    float tot = red[0]+red[1]+red[2]+red[3];
    if(j<100){
      tot += s0[0]*afw[6000*100+j] + s1[0]*afw[6001*100+j] + s2[0]*afw[6002*100+j] + afb[j];
    } else {
      tot += s0[0]*cfw[6000] + s1[0]*cfw[6001] + s2[0]*cfw[6002] + cfb[0];
    }
    out[j] = tot;
  }
}

extern "C" void kernel_launch(void* const* d_in, const int* in_sizes, int n_in,
                              void* d_out, int out_size, void* d_ws, size_t ws_size,
                              hipStream_t stream){
  const float* x   = (const float*)d_in[0];
  const int*   ei  = (const int*)d_in[1];
  const float* s0  = (const float*)d_in[2];
  const float* s1  = (const float*)d_in[3];
  const float* s2  = (const float*)d_in[4];
  const float* aw  = (const float*)d_in[5];
  const float* ab  = (const float*)d_in[6];
  const float* cw  = (const float*)d_in[7];
  const float* cb  = (const float*)d_in[8];
  const float* afw = (const float*)d_in[9];
  const float* afb = (const float*)d_in[10];
  const float* cfw = (const float*)d_in[11];
  const float* cfb = (const float*)d_in[12];
  float* out = (float*)d_out;

  float* Y   = (float*)d_ws;               // 6*100*60 fp32 split-K accumulators
  float* emb = Y + 6*NN*CO;                // 2*6000 fp32 tanh embeddings

  hipMemsetAsync(Y, 0, 6*NN*CO*sizeof(float), stream);
  k_gemm<<<dim3(NSPLIT,3), 256, 0, stream>>>(x, aw, cw, Y);
  k_cheb<<<120, 128, 0, stream>>>(Y, ei, ab, cb, emb);
  k_fc<<<101, 256, 0, stream>>>(emb, afw, afb, cfw, cfb, s0, s1, s2, out);
}

// Round 2
// 212.434 us; speedup vs baseline: 1.1997x; 1.1997x over previous
//
#include <hip/hip_runtime.h>
#include <stdint.h>

#define F_IN 65536
#define NN 100
#define CO 60
#define G_SPLIT 128
#define KC (F_IN/G_SPLIT)   // 512
#define BK 64
#define NIT (KC/BK)         // 8
#define AST 72              // A LDS row stride in shorts (144 B: 16B-aligned, 2-way bank alias = free)

typedef short v8s __attribute__((ext_vector_type(8)));
typedef float v4f __attribute__((ext_vector_type(4)));

__device__ __forceinline__ unsigned int f2bf(float x){
  unsigned int u = __float_as_uint(x);
  u += 0x7fffu + ((u>>16)&1u);      // round-to-nearest-even
  return u>>16;
}

__device__ __forceinline__ v4f mfma16(v8s a, v8s b, v4f c){
  return __builtin_amdgcn_mfma_f32_16x16x32_bf16(a,b,c,0,0,0);
}

// ---------------------------------------------------------------------------
// K1: split-K GEMM.  grid=(G_SPLIT, 6): blockIdx.y = matrix g (a0,a1,a2,c0,c1,c2).
// Software-pipelined: prefetch next tile's A(regs)+B(regs) behind current MFMA.
// Double-buffered LDS (one barrier/iter).  Epilogue: plain stores to split-K
// partial slab P[g][s][6000] (or atomicAdd fallback if ws too small).
// ---------------------------------------------------------------------------
__global__ __launch_bounds__(256,2)
void k_gemm(const float* __restrict__ x, const float* __restrict__ aw,
            const float* __restrict__ cw, float* __restrict__ dst, int partial){
  const int s  = blockIdx.x;
  const int g  = blockIdx.y;
  const int k0 = s*KC;
  const int tid = threadIdx.x;
  const int wave = tid>>6, lane = tid&63, quad = lane>>4, nl = lane&15;
  const int c0 = wave*16;
  const int ccl = min(c0+nl, CO-1);          // clamp pad cols; discarded at store

  const float* W  = (g<3) ? (aw + (size_t)g*F_IN*CO) : (cw + (size_t)(g-3)*F_IN*CO);
  const float* wp = W + (size_t)(k0 + quad*8)*CO + ccl;

  __shared__ __align__(16) unsigned short Al[2][112*AST];

  // staging geometry: thread covers 7 (row,q) cells; row=lin>>4, q=lin&15 (q = 4-float group)
  float4 ra[7];
  float  rb[16];
  #pragma unroll
  for(int p=0;p<7;++p){
    int lin = p*256 + tid, row = lin>>4, q = lin&15;
    int rcl = min(row, NN-1);
    ra[p] = *(const float4*)(x + (size_t)rcl*F_IN + k0 + q*4);
  }
  #pragma unroll
  for(int u=0;u<16;++u) rb[u] = wp[((u>>3)*32 + (u&7))*CO];

  v4f acc[7];
  #pragma unroll
  for(int i=0;i<7;++i){ v4f z={0.f,0.f,0.f,0.f}; acc[i]=z; }

  for(int it=0; it<NIT; ++it){
    unsigned short* buf = Al[it&1];
    // --- write prefetched A tile (bf16) ---
    #pragma unroll
    for(int p=0;p<7;++p){
      int lin = p*256 + tid, row = lin>>4, q = lin&15;
      uint2 w;
      w.x = f2bf(ra[p].x) | (f2bf(ra[p].y)<<16);
      w.y = f2bf(ra[p].z) | (f2bf(ra[p].w)<<16);
      *(uint2*)(buf + row*AST + q*4) = w;
    }
    // --- convert prefetched B to fragments ---
    v8s fB0, fB1;
    #pragma unroll
    for(int j=0;j<8;++j){
      fB0[j] = (short)f2bf(rb[j]);
      fB1[j] = (short)f2bf(rb[8+j]);
    }
    __syncthreads();
    // --- kick next iteration's global loads (in flight behind MFMA) ---
    if(it+1 < NIT){
      const int kb = k0 + (it+1)*BK;
      #pragma unroll
      for(int p=0;p<7;++p){
        int lin = p*256 + tid, row = lin>>4, q = lin&15;
        int rcl = min(row, NN-1);
        ra[p] = *(const float4*)(x + (size_t)rcl*F_IN + kb + q*4);
      }
      #pragma unroll
      for(int u=0;u<16;++u) rb[u] = wp[((it+1)*BK + (u>>3)*32 + (u&7))*CO];
    }
    // --- MFMA over 7 m-tiles (M padded 100->112) ---
    #pragma unroll
    for(int mt=0; mt<7; ++mt){
      const unsigned short* arow = buf + (mt*16+nl)*AST + quad*8;
      v8s a0 = *(const v8s*)(arow);
      v8s a1 = *(const v8s*)(arow+32);
      acc[mt] = mfma16(a0, fB0, acc[mt]);
      acc[mt] = mfma16(a1, fB1, acc[mt]);
    }
  }

  // --- epilogue.  C/D layout: col=lane&15, row=quad*4+i ---
  const int c = c0 + nl;
  if(c < CO){
    if(partial){
      float* pd = dst + ((size_t)g*G_SPLIT + s)*(NN*CO);
      #pragma unroll
      for(int mt=0;mt<7;++mt){
        #pragma unroll
        for(int i=0;i<4;++i){
          int m = mt*16 + quad*4 + i;
          if(m < NN) pd[m*CO + c] = acc[mt][i];
        }
      }
    } else {
      float* pd = dst + (size_t)g*(NN*CO);
      #pragma unroll
      for(int mt=0;mt<7;++mt){
        #pragma unroll
        for(int i=0;i<4;++i){
          int m = mt*16 + quad*4 + i;
          if(m < NN) atomicAdd(pd + m*CO + c, acc[mt][i]);
        }
      }
    }
  }
}

// ---------------------------------------------------------------------------
// K1b: split-K reduce.  grid=(141,4); block (b,q) sums 32 slices of P into Y
// via atomicAdd (Y zeroed by memset).  Reads coalesced (stride 6000 floats).
// ---------------------------------------------------------------------------
__global__ void k_reduce(const float* __restrict__ P, float* __restrict__ Y){
  int o = blockIdx.x*256 + threadIdx.x;
  if(o >= 6*NN*CO) return;
  int gg = o/(NN*CO), r = o - gg*(NN*CO);
  const float* p = P + (size_t)gg*G_SPLIT*(NN*CO) + (size_t)blockIdx.y*32*(NN*CO) + r;
  float a0=0.f,a1=0.f,a2=0.f,a3=0.f;
  #pragma unroll 2
  for(int s4=0;s4<32;s4+=4){
    a0 += p[(s4  )*(NN*CO)];
    a1 += p[(s4+1)*(NN*CO)];
    a2 += p[(s4+2)*(NN*CO)];
    a3 += p[(s4+3)*(NN*CO)];
  }
  atomicAdd(&Y[o], (a0+a1)+(a2+a3));
}

// ---------------------------------------------------------------------------
// K2: cheb combine.  out = Y0 - Y2 + L@(Y1 + 2*L@Y2) + b, then tanh.
// One block per (net, output column c).  L (100x100) rebuilt in LDS per block.
// ---------------------------------------------------------------------------
__global__ void k_cheb(const float* __restrict__ Y, const int* __restrict__ ei,
                       const float* __restrict__ ab, const float* __restrict__ cb,
                       float* __restrict__ emb){
  const int net = blockIdx.x / CO;
  const int c   = blockIdx.x % CO;
  const int t   = threadIdx.x;       // 128
  __shared__ float L[NN][NN+1];      // stride 101: 2-way bank alias only
  __shared__ float dis[NN];
  __shared__ int   deg[NN];
  __shared__ float y0[NN], y1[NN], y2[NN], zu[NN];

  for(int i=t;i<NN*(NN+1);i+=128) ((float*)L)[i]=0.f;
  if(t<NN) deg[t]=0;
  __syncthreads();
  for(int e=t;e<2000;e+=128) atomicAdd(&deg[ei[e]],1);
  __syncthreads();
  if(t<NN) dis[t] = deg[t]>0 ? rsqrtf((float)deg[t]) : 0.f;
  __syncthreads();
  for(int e=t;e<2000;e+=128){
    int s = ei[e], d = ei[2000+e];
    atomicAdd(&L[d][s], -dis[s]*dis[d]);
  }
  if(t<NN){
    const float* yb = Y + (size_t)net*3*NN*CO + t*CO + c;
    y0[t]=yb[0]; y1[t]=yb[NN*CO]; y2[t]=yb[2*NN*CO];
  }
  __syncthreads();
  if(t<NN){
    float s=0.f;
    #pragma unroll 4
    for(int j=0;j<NN;++j) s += L[t][j]*y2[j];
    zu[t] = y1[t] + 2.f*s;
  }
  __syncthreads();
  if(t<NN){
    float s=0.f;
    #pragma unroll 4
    for(int j=0;j<NN;++j) s += L[t][j]*zu[j];
    float b = (net==0) ? ab[c] : cb[c];
    emb[net*NN*CO + t*CO + c] = tanhf(y0[t] - y2[t] + s + b);
  }
}

// ---------------------------------------------------------------------------
// K3: final FC.  out zeroed by memset.  Blocks 0..24: coalesced logits
// partials (lane = output column j, 240 i-rows per block), atomicAdd.
// Block 25: value dot + biases + scalar extras.
// ---------------------------------------------------------------------------
#define FCB 25
__global__ void k_fc(const float* __restrict__ emb, const float* __restrict__ afw,
                     const float* __restrict__ afb, const float* __restrict__ cfw,
                     const float* __restrict__ cfb, const float* __restrict__ s0,
                     const float* __restrict__ s1, const float* __restrict__ s2,
                     float* __restrict__ out){
  const int b = blockIdx.x;
  const int t = threadIdx.x;         // 256
  if(b < FCB){
    const int jj = t & 127, half = t >> 7;
    if(jj < 100){
      const int i0 = b*240 + half*120;
      const float* w = afw + (size_t)i0*100 + jj;
      const float* e = emb + i0;
      float p = 0.f;
      #pragma unroll 4
      for(int i=0;i<120;++i) p += e[i]*w[(size_t)i*100];
      atomicAdd(&out[jj], p);
    }
  } else {
    float p = 0.f;
    const float* e = emb + 6000;
    for(int i=t;i<6000;i+=256) p += e[i]*cfw[i];
    #pragma unroll
    for(int o=32;o>0;o>>=1) p += __shfl_down(p,o,64);
    __shared__ float red[4];
    if((t&63)==0) red[t>>6]=p;
    __syncthreads();
    if(t==0){
      float tot = red[0]+red[1]+red[2]+red[3];
      out[100] = tot + s0[0]*cfw[6000] + s1[0]*cfw[6001] + s2[0]*cfw[6002] + cfb[0];
    }
    if(t<100){
      atomicAdd(&out[t], afb[t] + s0[0]*afw[600000+t] + s1[0]*afw[600100+t] + s2[0]*afw[600200+t]);
    }
  }
}

extern "C" void kernel_launch(void* const* d_in, const int* in_sizes, int n_in,
                              void* d_out, int out_size, void* d_ws, size_t ws_size,
                              hipStream_t stream){
  const float* x   = (const float*)d_in[0];
  const int*   ei  = (const int*)d_in[1];
  const float* s0  = (const float*)d_in[2];
  const float* s1  = (const float*)d_in[3];
  const float* s2  = (const float*)d_in[4];
  const float* aw  = (const float*)d_in[5];
  const float* ab  = (const float*)d_in[6];
  const float* cw  = (const float*)d_in[7];
  const float* cb  = (const float*)d_in[8];
  const float* afw = (const float*)d_in[9];
  const float* afb = (const float*)d_in[10];
  const float* cfw = (const float*)d_in[11];
  const float* cfb = (const float*)d_in[12];
  float* out = (float*)d_out;

  float* Y   = (float*)d_ws;                       // [6][6000] reduced GEMM outputs
  float* emb = Y + 6*NN*CO;                        // [2][6000] tanh embeddings
  float* P   = emb + 2*NN*CO;                      // [6][G_SPLIT][6000] split-K partials
  const size_t need = (size_t)(6*NN*CO + 2*NN*CO + (size_t)6*G_SPLIT*NN*CO)*sizeof(float);
  const int partial = (ws_size >= need) ? 1 : 0;

  hipMemsetAsync(Y, 0, 6*NN*CO*sizeof(float), stream);
  hipMemsetAsync(out, 0, 101*sizeof(float), stream);

  k_gemm<<<dim3(G_SPLIT,6), 256, 0, stream>>>(x, aw, cw, partial ? P : Y, partial);
  if(partial){
    k_reduce<<<dim3((6*NN*CO+255)/256, 4), 256, 0, stream>>>(P, Y);
  }
  k_cheb<<<120, 128, 0, stream>>>(Y, ei, ab, cb, emb);
  k_fc<<<FCB+1, 256, 0, stream>>>(emb, afw, afb, cfw, cfb, s0, s1, s2, out);
}